// Round 2
// baseline (14975.758 us; speedup 1.0000x reference)
//
#include <hip/hip_runtime.h>
#include <hip/hip_fp16.h>

typedef _Float16 h16;
typedef __attribute__((ext_vector_type(4))) _Float16 h16x4;
typedef __attribute__((ext_vector_type(8))) _Float16 h16x8;
typedef __attribute__((ext_vector_type(4))) float f32x4;

#define T_SEQ 512
#define NB    64
#define NI    512
#define NH    1024
#define N3H   3072

// ============================================================
// Kernel 0: initialize h^(0) hi/lo f16 planes (parity-0 buffer)
// ============================================================
__global__ void gru_init_h(const float* __restrict__ hid0,
                           h16* __restrict__ hhi, h16* __restrict__ hlo) {
  int k = blockIdx.x * blockDim.x + threadIdx.x;
  if (k >= NH) return;
  float v = hid0[k];               // hid_init is [1,H], broadcast over batch
  h16 hi = (h16)v;
  h16 lo = (h16)(v - (float)hi);
  #pragma unroll 4
  for (int b = 0; b < NB; ++b) {
    hhi[b * NH + k] = hi;
    hlo[b * NH + k] = lo;
  }
}

// ============================================================
// Kernel 1: x[t][b][3H] = inp[b][t][:] @ W_in + b_stacked  (f16 out)
// 128x128 tile, BK=32, 4 waves, split-f16 3-term MFMA (~f32 accuracy).
// A rows m = t*64 + b so output rows are already [T][B] order.
// ============================================================
#define P1_BM 128
#define P1_BK 32

// XOR-swizzled half-index inside a [128][32] f16 plane (64B rows).
__device__ __forceinline__ int p1swz(int r, int k) {
  return r * P1_BK + ((((k >> 3) ^ (r & 3)) << 3) | (k & 7));
}

__global__ __launch_bounds__(256, 2) void gru_xgemm(
    const float* __restrict__ inp, const float* __restrict__ Win,
    const float* __restrict__ bstk, h16* __restrict__ x) {
  __shared__ h16 sAh[2][P1_BM * P1_BK];
  __shared__ h16 sAl[2][P1_BM * P1_BK];
  __shared__ h16 sBh[2][P1_BM * P1_BK];
  __shared__ h16 sBl[2][P1_BM * P1_BK];   // total exactly 64 KiB

  const int tid = threadIdx.x;
  const int l = tid & 63;
  const int w = tid >> 6;
  const int wm = (w >> 1) * 64, wn = (w & 1) * 64;
  const int mi = blockIdx.x, ni = blockIdx.y;
  const int n0 = ni * 128;

  // staging assignment: thread -> (row/n = tid>>1, 16-wide k chunk)
  const int sr  = tid >> 1;
  const int skh = (tid & 1) * 16;

  // A source: tile row r -> inp[b=(r&63)][t=mi*2+(r>>6)][k]
  const float* aSrcBase = inp + (size_t)(sr & 63) * (T_SEQ * NI)
                              + (size_t)(mi * 2 + (sr >> 6)) * NI + skh;
  // B source: Win[k][n0+sr]
  const float* bSrcBase = Win + (size_t)skh * N3H + n0 + sr;

  f32x4 acc[4][4] = {};
  float aReg[16];
  float bReg[16];

  auto stage_load = [&](int ks) {
    const float* ap = aSrcBase + ks * P1_BK;
    #pragma unroll
    for (int jg = 0; jg < 4; ++jg) {
      f32x4 v = *(const f32x4*)(ap + jg * 4);
      aReg[jg*4+0] = v[0]; aReg[jg*4+1] = v[1];
      aReg[jg*4+2] = v[2]; aReg[jg*4+3] = v[3];
    }
    const float* bp = bSrcBase + (size_t)ks * P1_BK * N3H;
    #pragma unroll
    for (int j = 0; j < 16; ++j) bReg[j] = bp[(size_t)j * N3H];
  };

  auto stage_write = [&](int buf) {
    #pragma unroll
    for (int jg = 0; jg < 4; ++jg) {
      int idx = p1swz(sr, skh + jg * 4);
      h16x4 hi, lo;
      #pragma unroll
      for (int j = 0; j < 4; ++j) {
        float v = aReg[jg*4+j];
        h16 h = (h16)v; hi[j] = h; lo[j] = (h16)(v - (float)h);
      }
      *(h16x4*)&sAh[buf][idx] = hi;
      *(h16x4*)&sAl[buf][idx] = lo;
      #pragma unroll
      for (int j = 0; j < 4; ++j) {
        float v = bReg[jg*4+j];
        h16 h = (h16)v; hi[j] = h; lo[j] = (h16)(v - (float)h);
      }
      *(h16x4*)&sBh[buf][idx] = hi;   // B stored transposed: [n][k]
      *(h16x4*)&sBl[buf][idx] = lo;
    }
  };

  auto compute = [&](int buf) {
    const int k0 = (l >> 4) * 8;
    h16x8 bh[4], bl[4];
    #pragma unroll
    for (int nt = 0; nt < 4; ++nt) {
      int idx = p1swz(wn + nt * 16 + (l & 15), k0);
      bh[nt] = *(const h16x8*)&sBh[buf][idx];
      bl[nt] = *(const h16x8*)&sBl[buf][idx];
    }
    #pragma unroll
    for (int mt = 0; mt < 4; ++mt) {
      int idx = p1swz(wm + mt * 16 + (l & 15), k0);
      h16x8 ah = *(const h16x8*)&sAh[buf][idx];
      h16x8 al = *(const h16x8*)&sAl[buf][idx];
      #pragma unroll
      for (int nt = 0; nt < 4; ++nt) {
        acc[mt][nt] = __builtin_amdgcn_mfma_f32_16x16x32_f16(ah, bh[nt], acc[mt][nt], 0, 0, 0);
        acc[mt][nt] = __builtin_amdgcn_mfma_f32_16x16x32_f16(ah, bl[nt], acc[mt][nt], 0, 0, 0);
        acc[mt][nt] = __builtin_amdgcn_mfma_f32_16x16x32_f16(al, bh[nt], acc[mt][nt], 0, 0, 0);
      }
    }
  };

  stage_load(0);
  stage_write(0);
  __syncthreads();
  for (int ks = 0; ks < 16; ++ks) {
    int buf = ks & 1;
    if (ks < 15) stage_load(ks + 1);   // issue globals early
    compute(buf);
    if (ks < 15) stage_write(buf ^ 1); // ds_write after MFMAs hide vmem latency
    __syncthreads();
  }

  const size_t m0 = (size_t)mi * P1_BM;
  #pragma unroll
  for (int nt = 0; nt < 4; ++nt) {
    int col = n0 + wn + nt * 16 + (l & 15);
    float bias = bstk[col];
    #pragma unroll
    for (int mt = 0; mt < 4; ++mt) {
      #pragma unroll
      for (int i = 0; i < 4; ++i) {
        size_t row = m0 + wm + mt * 16 + (l >> 4) * 4 + i;   // row = t*64+b
        x[row * N3H + col] = (h16)(acc[mt][nt][i] + bias);
      }
    }
  }
}

// ============================================================
// Kernel 2: persistent GRU recurrence.
// Grid 256 = 64 col-groups (16 h-cols) x 4 batch-groups (16 rows).
// 3 waves/WG: wave g computes gate g's 16x16 pre-activation tile.
// W_hid slice (f16, MFMA-fragment order) lives in 96KB STATIC LDS for
// all 512 steps. h kept as f16 hi/lo planes, step-parity double buffer.
// Cross-WG sync: per-(cg,bg) flags, agent-scope release/acquire.
// ============================================================
__global__ __launch_bounds__(192, 1) void gru_steps(
    const float* __restrict__ Whid,   // [1024][3072] f32
    const h16* __restrict__ x,        // [512][64][3072] f16
    h16* __restrict__ hbuf,           // [2 parity][2 plane][64][1024] f16
    unsigned* __restrict__ flags,     // [64 cg][4 bg]
    float* __restrict__ out) {        // [64][1024] f32
  __shared__ h16 U[3 * 32 * 64 * 8];  // 96 KiB, fragment-ordered W_hid slice
  __shared__ float rbuf[16 * 17];
  __shared__ float ubuf[16 * 17];

  const int tid = threadIdx.x;
  const int l = tid & 63;
  const int g = tid >> 6;                 // wave = gate (0=r,1=u,2=c)
  const int cg = blockIdx.x & 63;
  const int bg = blockIdx.x >> 6;
  const int hstride = NB * NH;            // 65536 elems per plane

  // ---- one-time: load this WG's W_hid slice into fragment-ordered LDS ----
  {
    const float* base = Whid + (size_t)g * NH + (size_t)cg * 16 + (l & 15);
    for (int kt = 0; kt < 32; ++kt) {
      const float* src = base + (size_t)(kt * 32 + (l >> 4) * 8) * N3H;
      h16x8 v;
      #pragma unroll
      for (int j = 0; j < 8; ++j) v[j] = (h16)src[(size_t)j * N3H];
      *(h16x8*)&U[(size_t)((g * 32 + kt) * 64 + l) * 8] = v;
    }
  }
  __syncthreads();

  const int arow = bg * 16 + (l & 15);
  const int k0 = (l >> 4) * 8;

  for (int s = 1; s <= T_SEQ; ++s) {
    // ---- wait for all 64 col-groups of our batch-group at step s-1 ----
    unsigned tgt = (unsigned)(s - 1);
    long spin = 0;
    for (;;) {
      unsigned v = __hip_atomic_load(&flags[l * 4 + bg], __ATOMIC_RELAXED,
                                     __HIP_MEMORY_SCOPE_AGENT);
      if (__all((int)(v >= tgt))) break;
      __builtin_amdgcn_s_sleep(1);
      if (++spin > 200000) break;   // hang-safety: prefer wrong over deadlock
    }
    __builtin_amdgcn_fence(__ATOMIC_ACQUIRE, "agent");

    const h16* hp_hi = hbuf + (size_t)((s - 1) & 1) * 2 * hstride;
    const h16* hp_lo = hp_hi + hstride;

    // ---- hid = (h_hi + h_lo) @ U_gate  (2-term split-f16, f32 acc) ----
    f32x4 a0 = {}, a1 = {}, a2 = {}, a3 = {};
    const h16* arow_hi = hp_hi + (size_t)arow * NH + k0;
    const h16* arow_lo = hp_lo + (size_t)arow * NH + k0;
    #pragma unroll 4
    for (int kt = 0; kt < 32; ++kt) {
      h16x8 ah = *(const h16x8*)(arow_hi + kt * 32);
      h16x8 al = *(const h16x8*)(arow_lo + kt * 32);
      h16x8 b  = *(const h16x8*)&U[(size_t)((g * 32 + kt) * 64 + l) * 8];
      if (kt & 1) {
        a1 = __builtin_amdgcn_mfma_f32_16x16x32_f16(ah, b, a1, 0, 0, 0);
        a3 = __builtin_amdgcn_mfma_f32_16x16x32_f16(al, b, a3, 0, 0, 0);
      } else {
        a0 = __builtin_amdgcn_mfma_f32_16x16x32_f16(ah, b, a0, 0, 0, 0);
        a2 = __builtin_amdgcn_mfma_f32_16x16x32_f16(al, b, a2, 0, 0, 0);
      }
    }
    f32x4 hid;
    #pragma unroll
    for (int i = 0; i < 4; ++i) hid[i] = (a0[i] + a2[i]) + (a1[i] + a3[i]);

    // ---- x_t tile for this gate (C layout: col=l&15, row=(l>>4)*4+i) ----
    const h16* xp = x + ((size_t)(s - 1) * NB + bg * 16) * N3H
                      + (size_t)g * NH + cg * 16 + (l & 15);
    float xv[4];
    #pragma unroll
    for (int i = 0; i < 4; ++i)
      xv[i] = (float)xp[(size_t)((l >> 4) * 4 + i) * N3H];

    if (g == 0) {
      #pragma unroll
      for (int i = 0; i < 4; ++i) {
        float p = xv[i] + hid[i];
        rbuf[((l >> 4) * 4 + i) * 17 + (l & 15)] = 1.0f / (1.0f + __expf(-p));
      }
    } else if (g == 1) {
      #pragma unroll
      for (int i = 0; i < 4; ++i) {
        float p = xv[i] + hid[i];
        ubuf[((l >> 4) * 4 + i) * 17 + (l & 15)] = 1.0f / (1.0f + __expf(-p));
      }
    }
    __syncthreads();   // r,u tiles visible to wave 2

    if (g == 2) {
      h16* wp_hi = hbuf + (size_t)(s & 1) * 2 * hstride;
      h16* wp_lo = wp_hi + hstride;
      #pragma unroll
      for (int i = 0; i < 4; ++i) {
        int rr = (l >> 4) * 4 + i, cc = l & 15;
        float r = rbuf[rr * 17 + cc];
        float u = ubuf[rr * 17 + cc];
        float c = tanhf(xv[i] + r * hid[i]);
        int row = bg * 16 + rr, col = cg * 16 + cc;
        float hprev = (float)hp_hi[(size_t)row * NH + col]
                    + (float)hp_lo[(size_t)row * NH + col];
        float hn = (1.0f - u) * hprev + u * c;
        h16 hi = (h16)hn;
        h16 lo = (h16)(hn - (float)hi);
        wp_hi[(size_t)row * NH + col] = hi;
        wp_lo[(size_t)row * NH + col] = lo;
        if (s == T_SEQ) out[(size_t)row * NH + col] = hn;
      }
      __builtin_amdgcn_fence(__ATOMIC_RELEASE, "agent");
      if (l == 0)
        __hip_atomic_store(&flags[cg * 4 + bg], (unsigned)s, __ATOMIC_RELEASE,
                           __HIP_MEMORY_SCOPE_AGENT);
    }
    __syncthreads();   // protect rbuf/ubuf reuse next step
  }
}

// ============================================================
extern "C" void kernel_launch(void* const* d_in, const int* in_sizes, int n_in,
                              void* d_out, int out_size, void* d_ws, size_t ws_size,
                              hipStream_t stream) {
  const float* inp  = (const float*)d_in[0];
  const float* Win  = (const float*)d_in[1];
  const float* Whid = (const float*)d_in[2];
  const float* bstk = (const float*)d_in[3];
  const float* hid0 = (const float*)d_in[4];
  float* out = (float*)d_out;

  char* ws = (char*)d_ws;
  const size_t xBytes = (size_t)T_SEQ * NB * N3H * sizeof(h16);   // 201,326,592
  const size_t hBytes = (size_t)2 * 2 * NB * NH * sizeof(h16);    //     524,288
  const size_t fBytes = 64 * 4 * sizeof(unsigned);                //       1,024
  if (ws_size < xBytes + hBytes + fBytes) return;  // clean numeric fail, no fault

  h16* x = (h16*)ws;
  h16* hbuf = (h16*)(ws + xBytes);
  unsigned* flags = (unsigned*)(ws + xBytes + hBytes);

  hipMemsetAsync(flags, 0, fBytes, stream);

  gru_init_h<<<dim3((NH + 255) / 256), dim3(256), 0, stream>>>(
      hid0, hbuf, hbuf + NB * NH);

  dim3 g1(32768 / P1_BM, N3H / 128);
  gru_xgemm<<<g1, dim3(256), 0, stream>>>(inp, Win, bstk, x);

  gru_steps<<<dim3(256), dim3(192), 0, stream>>>(Whid, x, hbuf, flags, out);
}

// Round 4
// 5027.201 us; speedup vs baseline: 2.9789x; 2.9789x over previous
//
#include <hip/hip_runtime.h>
#include <hip/hip_fp16.h>

typedef _Float16 h16;
typedef __attribute__((ext_vector_type(4))) _Float16 h16x4;
typedef __attribute__((ext_vector_type(8))) _Float16 h16x8;
typedef __attribute__((ext_vector_type(4))) float f32x4;
typedef unsigned long long u64;

#define T_SEQ 512
#define NB    64
#define NI    512
#define NH    1024
#define N3H   3072

// Coherent (agent-scope, cross-XCD) access helpers: per-access coherence,
// NO cache-wide fences (the round-2 killer: buffer_inv/wbl2 per step).
__device__ __forceinline__ u64 cload64(const u64* p) {
  return __hip_atomic_load(p, __ATOMIC_RELAXED, __HIP_MEMORY_SCOPE_AGENT);
}
__device__ __forceinline__ void cstore16(unsigned short* p, unsigned short v) {
  __hip_atomic_store(p, v, __ATOMIC_RELAXED, __HIP_MEMORY_SCOPE_AGENT);
}
__device__ __forceinline__ void cstore32(unsigned* p, unsigned v) {
  __hip_atomic_store(p, v, __ATOMIC_RELAXED, __HIP_MEMORY_SCOPE_AGENT);
}

union H4 { u64 q; h16x4 v; };
union HS { h16 h; unsigned short u; };

// ============================================================
// Kernel 0: initialize h^(0) hi/lo f16 planes (parity-0 buffer)
// ============================================================
__global__ void gru_init_h(const float* __restrict__ hid0,
                           h16* __restrict__ hhi, h16* __restrict__ hlo) {
  int k = blockIdx.x * blockDim.x + threadIdx.x;
  if (k >= NH) return;
  float v = hid0[k];
  h16 hi = (h16)v;
  h16 lo = (h16)(v - (float)hi);
  #pragma unroll 4
  for (int b = 0; b < NB; ++b) {
    hhi[b * NH + k] = hi;
    hlo[b * NH + k] = lo;
  }
}

// ============================================================
// Kernel 1: x = inp @ W_in + b  (f16 out, CONSUMER-TRANSPOSED layout)
// x layout: [t][gate][cg][bg][cc*16 + rr]  (512B block per (t,g,cg,bg))
// so gru_steps reads its whole per-step tile as ONE 8B load per lane.
// ============================================================
#define P1_BM 128
#define P1_BK 32

__device__ __forceinline__ int p1swz(int r, int k) {
  return r * P1_BK + ((((k >> 3) ^ (r & 3)) << 3) | (k & 7));
}

__global__ __launch_bounds__(256, 2) void gru_xgemm(
    const float* __restrict__ inp, const float* __restrict__ Win,
    const float* __restrict__ bstk, h16* __restrict__ x) {
  __shared__ h16 sAh[2][P1_BM * P1_BK];
  __shared__ h16 sAl[2][P1_BM * P1_BK];
  __shared__ h16 sBh[2][P1_BM * P1_BK];
  __shared__ h16 sBl[2][P1_BM * P1_BK];

  const int tid = threadIdx.x;
  const int l = tid & 63;
  const int w = tid >> 6;
  const int wm = (w >> 1) * 64, wn = (w & 1) * 64;
  const int mi = blockIdx.x, ni = blockIdx.y;

  const int sr  = tid >> 1;
  const int skh = (tid & 1) * 16;

  const float* aSrcBase = inp + (size_t)(sr & 63) * (T_SEQ * NI)
                              + (size_t)(mi * 2 + (sr >> 6)) * NI + skh;
  const float* bSrcBase = Win + (size_t)skh * N3H + ni * 128 + sr;

  f32x4 acc[4][4] = {};
  float aReg[16];
  float bReg[16];

  auto stage_load = [&](int ks) {
    const float* ap = aSrcBase + ks * P1_BK;
    #pragma unroll
    for (int jg = 0; jg < 4; ++jg) {
      f32x4 v = *(const f32x4*)(ap + jg * 4);
      aReg[jg*4+0] = v[0]; aReg[jg*4+1] = v[1];
      aReg[jg*4+2] = v[2]; aReg[jg*4+3] = v[3];
    }
    const float* bp = bSrcBase + (size_t)ks * P1_BK * N3H;
    #pragma unroll
    for (int j = 0; j < 16; ++j) bReg[j] = bp[(size_t)j * N3H];
  };

  auto stage_write = [&](int buf) {
    #pragma unroll
    for (int jg = 0; jg < 4; ++jg) {
      int idx = p1swz(sr, skh + jg * 4);
      h16x4 hi, lo;
      #pragma unroll
      for (int j = 0; j < 4; ++j) {
        float v = aReg[jg*4+j];
        h16 h = (h16)v; hi[j] = h; lo[j] = (h16)(v - (float)h);
      }
      *(h16x4*)&sAh[buf][idx] = hi;
      *(h16x4*)&sAl[buf][idx] = lo;
      #pragma unroll
      for (int j = 0; j < 4; ++j) {
        float v = bReg[jg*4+j];
        h16 h = (h16)v; hi[j] = h; lo[j] = (h16)(v - (float)h);
      }
      *(h16x4*)&sBh[buf][idx] = hi;
      *(h16x4*)&sBl[buf][idx] = lo;
    }
  };

  auto compute = [&](int buf) {
    const int k0 = (l >> 4) * 8;
    h16x8 bh[4], bl[4];
    #pragma unroll
    for (int nt = 0; nt < 4; ++nt) {
      int idx = p1swz(wn + nt * 16 + (l & 15), k0);
      bh[nt] = *(const h16x8*)&sBh[buf][idx];
      bl[nt] = *(const h16x8*)&sBl[buf][idx];
    }
    #pragma unroll
    for (int mt = 0; mt < 4; ++mt) {
      int idx = p1swz(wm + mt * 16 + (l & 15), k0);
      h16x8 ah = *(const h16x8*)&sAh[buf][idx];
      h16x8 al = *(const h16x8*)&sAl[buf][idx];
      #pragma unroll
      for (int nt = 0; nt < 4; ++nt) {
        acc[mt][nt] = __builtin_amdgcn_mfma_f32_16x16x32_f16(ah, bh[nt], acc[mt][nt], 0, 0, 0);
        acc[mt][nt] = __builtin_amdgcn_mfma_f32_16x16x32_f16(ah, bl[nt], acc[mt][nt], 0, 0, 0);
        acc[mt][nt] = __builtin_amdgcn_mfma_f32_16x16x32_f16(al, bh[nt], acc[mt][nt], 0, 0, 0);
      }
    }
  };

  stage_load(0);
  stage_write(0);
  __syncthreads();
  for (int ks = 0; ks < 16; ++ks) {
    int buf = ks & 1;
    if (ks < 15) stage_load(ks + 1);
    compute(buf);
    if (ks < 15) stage_write(buf ^ 1);
    __syncthreads();
  }

  // Epilogue: store into consumer-transposed layout.
  const int t = mi * 2 + (wm >> 6);
  const int rrb = (l >> 4) * 4;
  #pragma unroll
  for (int nt = 0; nt < 4; ++nt) {
    int colhi = ni * 8 + (wn >> 4) + nt;
    int gg  = colhi >> 6;
    int cgx = colhi & 63;
    float bias = bstk[(colhi << 4) + (l & 15)];
    #pragma unroll
    for (int mt = 0; mt < 4; ++mt) {
      h16x4 v;
      #pragma unroll
      for (int i = 0; i < 4; ++i) v[i] = (h16)(acc[mt][nt][i] + bias);
      size_t idx = ((((size_t)t * 3 + gg) * 64 + cgx) * 4 + mt) * 256
                 + (size_t)(l & 15) * 16 + rrb;
      *(h16x4*)&x[idx] = v;
    }
  }
}

// ============================================================
// Kernel 2: persistent GRU recurrence — fence-free coherent sync.
// Grid 256 = 64 cg x 4 bg, 3 waves (one per gate), 1 WG/CU.
// Per step: stage h_hi -> LDS (4096 coherent u64, coalesced), MFMA-hi
// while h_lo loads fly, stage lo, MFMA-lo, gates, atomic h store,
// vmcnt(0), flag store. No cache-wide fences anywhere.
// ============================================================
__global__ __launch_bounds__(192, 1) void gru_steps(
    const float* __restrict__ Whid,   // [1024][3072] f32
    const h16* __restrict__ x,        // transposed layout, f16
    h16* __restrict__ hbuf,           // [2 parity][2 plane][64][1024] f16
    unsigned* __restrict__ flags,     // [64 cg][4 bg]
    float* __restrict__ out) {        // [64][1024] f32
  __shared__ h16 U[3 * 32 * 64 * 8];  // 96 KiB fragment-ordered W_hid slice
  __shared__ h16 hstage[16 * 1024];   // 32 KiB staged h plane (XOR-swizzled)
  __shared__ float rbuf[2][16 * 17];
  __shared__ float ubuf[2][16 * 17];  // parity-dbuf'd r/u exchange

  const int tid = threadIdx.x;
  const int l = tid & 63;
  const int g = tid >> 6;
  const int cg = blockIdx.x & 63;
  const int bg = blockIdx.x >> 6;
  const int hstride = NB * NH;

  // ---- one-time: W_hid slice -> fragment-ordered LDS ----
  {
    const float* base = Whid + (size_t)g * NH + (size_t)cg * 16 + (l & 15);
    for (int kt = 0; kt < 32; ++kt) {
      const float* src = base + (size_t)(kt * 32 + (l >> 4) * 8) * N3H;
      h16x8 v;
      #pragma unroll
      for (int j = 0; j < 8; ++j) v[j] = (h16)src[(size_t)j * N3H];
      *(h16x8*)&U[(size_t)((g * 32 + kt) * 64 + l) * 8] = v;
    }
  }

  // ---- wave2: persistent h_prev registers (owner-only tile) ----
  float hq[4];
  if (g == 2) {
    #pragma unroll
    for (int i = 0; i < 4; ++i) {
      int row = bg * 16 + (l >> 4) * 4 + i, col = cg * 16 + (l & 15);
      hq[i] = (float)hbuf[(size_t)row * NH + col]
            + (float)hbuf[(size_t)hstride + row * NH + col];
    }
  }
  __syncthreads();

  // x pointer for this wave (one 8B load per step)
  const char* xb = (const char*)(x
      + ((((size_t)g * 64 + cg) * 4 + bg) * 256)
      + (size_t)(l & 15) * 16 + (l >> 4) * 4);
  u64 xq = *(const u64*)xb;   // step 1 tile, prefetched

  for (int s = 1; s <= T_SEQ; ++s) {
    // ---- spin: all 64 cg of our bg done with step s-1 ----
    const unsigned tgt = (unsigned)(s - 1);
    int spincnt = 0;
    for (;;) {
      unsigned v = __hip_atomic_load(&flags[l * 4 + bg], __ATOMIC_RELAXED,
                                     __HIP_MEMORY_SCOPE_AGENT);
      if (__all((int)(v >= tgt))) break;
      __builtin_amdgcn_s_sleep(1);
      if (++spincnt > 30000) break;   // hang-safety
    }
    __builtin_amdgcn_sched_barrier(0);

    const h16* hp_hi = hbuf + (size_t)((s - 1) & 1) * 2 * hstride;
    const u64* srcHi = (const u64*)(hp_hi + (size_t)bg * 16 * NH);
    const u64* srcLo = srcHi + (hstride >> 2);

    // ---- phase A: stage hi plane (4096 u64 = 16 rows x 256 u64) ----
    u64 tmp[22];
    #pragma unroll
    for (int k = 0; k < 22; ++k) {
      int wd = tid + 192 * k;
      tmp[k] = (wd < 4096) ? cload64(srcHi + wd) : 0;
    }
    #pragma unroll
    for (int k = 0; k < 22; ++k) {
      int wd = tid + 192 * k;
      if (wd < 4096) {
        int row = wd >> 8, cb = (wd & 255) * 8;
        *(u64*)((char*)hstage + row * 2048 + (cb ^ ((row & 7) << 4))) = tmp[k];
      }
    }
    __syncthreads();   // b1: hi staged

    // ---- issue lo loads now; they drain under MFMA-hi ----
    u64 tmpl[22];
    #pragma unroll
    for (int k = 0; k < 22; ++k) {
      int wd = tid + 192 * k;
      tmpl[k] = (wd < 4096) ? cload64(srcLo + wd) : 0;
    }
    // prefetch next step's x tile (plain cached load)
    u64 xq_next = xq;
    if (s < T_SEQ) xq_next = *(const u64*)(xb + (size_t)s * 393216);

    // ---- MFMA hi ----
    f32x4 a0 = {}, a1 = {};
    #pragma unroll 4
    for (int kt = 0; kt < 32; ++kt) {
      int ab = (l & 15) * 2048 + ((kt * 64 + (l >> 4) * 16) ^ ((l & 7) << 4));
      h16x8 ah = *(const h16x8*)((const char*)hstage + ab);
      h16x8 b  = *(const h16x8*)&U[(size_t)((g * 32 + kt) * 64 + l) * 8];
      if (kt & 1) a1 = __builtin_amdgcn_mfma_f32_16x16x32_f16(ah, b, a1, 0, 0, 0);
      else        a0 = __builtin_amdgcn_mfma_f32_16x16x32_f16(ah, b, a0, 0, 0, 0);
    }
    __syncthreads();   // b2: done reading hstage (WAR for lo write)

    #pragma unroll
    for (int k = 0; k < 22; ++k) {
      int wd = tid + 192 * k;
      if (wd < 4096) {
        int row = wd >> 8, cb = (wd & 255) * 8;
        *(u64*)((char*)hstage + row * 2048 + (cb ^ ((row & 7) << 4))) = tmpl[k];
      }
    }
    __syncthreads();   // b3: lo staged

    // ---- MFMA lo ----
    f32x4 a2 = {}, a3 = {};
    #pragma unroll 4
    for (int kt = 0; kt < 32; ++kt) {
      int ab = (l & 15) * 2048 + ((kt * 64 + (l >> 4) * 16) ^ ((l & 7) << 4));
      h16x8 al = *(const h16x8*)((const char*)hstage + ab);
      h16x8 b  = *(const h16x8*)&U[(size_t)((g * 32 + kt) * 64 + l) * 8];
      if (kt & 1) a3 = __builtin_amdgcn_mfma_f32_16x16x32_f16(al, b, a3, 0, 0, 0);
      else        a2 = __builtin_amdgcn_mfma_f32_16x16x32_f16(al, b, a2, 0, 0, 0);
    }

    f32x4 hid;
    #pragma unroll
    for (int i = 0; i < 4; ++i) hid[i] = (a0[i] + a1[i]) + (a2[i] + a3[i]);

    H4 xc; xc.q = xq;
    const int p = s & 1;
    const int rr0 = (l >> 4) * 4, cc = l & 15;

    if (g == 0) {
      #pragma unroll
      for (int i = 0; i < 4; ++i) {
        float pr = (float)xc.v[i] + hid[i];
        rbuf[p][(rr0 + i) * 17 + cc] = 1.0f / (1.0f + __expf(-pr));
      }
    } else if (g == 1) {
      #pragma unroll
      for (int i = 0; i < 4; ++i) {
        float pu = (float)xc.v[i] + hid[i];
        ubuf[p][(rr0 + i) * 17 + cc] = 1.0f / (1.0f + __expf(-pu));
      }
    }
    __syncthreads();   // b4: r,u visible to wave 2

    if (g == 2) {
      h16* wp_hi = hbuf + (size_t)(s & 1) * 2 * hstride;
      h16* wp_lo = wp_hi + hstride;
      #pragma unroll
      for (int i = 0; i < 4; ++i) {
        int rr = rr0 + i;
        float r = rbuf[p][rr * 17 + cc];
        float u = ubuf[p][rr * 17 + cc];
        float c = tanhf((float)xc.v[i] + r * hid[i]);
        float hn = (1.0f - u) * hq[i] + u * c;
        hq[i] = hn;
        int row = bg * 16 + rr, col = cg * 16 + cc;
        HS hi, lo;
        hi.h = (h16)hn;
        lo.h = (h16)(hn - (float)hi.h);
        cstore16((unsigned short*)&wp_hi[(size_t)row * NH + col], hi.u);
        cstore16((unsigned short*)&wp_lo[(size_t)row * NH + col], lo.u);
        if (s == T_SEQ) out[(size_t)row * NH + col] = hn;
      }
      asm volatile("s_waitcnt vmcnt(0)" ::: "memory");   // h at coherence point
      if (l == 0) cstore32(&flags[cg * 4 + bg], (unsigned)s);
    }
    xq = xq_next;
  }
}

// ============================================================
extern "C" void kernel_launch(void* const* d_in, const int* in_sizes, int n_in,
                              void* d_out, int out_size, void* d_ws, size_t ws_size,
                              hipStream_t stream) {
  const float* inp  = (const float*)d_in[0];
  const float* Win  = (const float*)d_in[1];
  const float* Whid = (const float*)d_in[2];
  const float* bstk = (const float*)d_in[3];
  const float* hid0 = (const float*)d_in[4];
  float* out = (float*)d_out;

  char* ws = (char*)d_ws;
  const size_t xBytes = (size_t)T_SEQ * NB * N3H * sizeof(h16);   // 201,326,592
  const size_t hBytes = (size_t)2 * 2 * NB * NH * sizeof(h16);    //     524,288
  const size_t fBytes = 64 * 4 * sizeof(unsigned);                //       1,024
  if (ws_size < xBytes + hBytes + fBytes) return;

  h16* x = (h16*)ws;
  h16* hbuf = (h16*)(ws + xBytes);
  unsigned* flags = (unsigned*)(ws + xBytes + hBytes);

  hipMemsetAsync(flags, 0, fBytes, stream);

  gru_init_h<<<dim3((NH + 255) / 256), dim3(256), 0, stream>>>(
      hid0, hbuf, hbuf + NB * NH);

  dim3 g1(32768 / P1_BM, N3H / 128);
  gru_xgemm<<<g1, dim3(256), 0, stream>>>(inp, Win, bstk, x);

  gru_steps<<<dim3(256), dim3(192), 0, stream>>>(Whid, x, hbuf, flags, out);
}

// Round 5
// 3906.220 us; speedup vs baseline: 3.8338x; 1.2870x over previous
//
#include <hip/hip_runtime.h>
#include <hip/hip_fp16.h>

typedef _Float16 h16;
typedef __attribute__((ext_vector_type(4))) _Float16 h16x4;
typedef __attribute__((ext_vector_type(8))) _Float16 h16x8;
typedef __attribute__((ext_vector_type(4))) float f32x4;
typedef unsigned long long u64;

#define T_SEQ 512
#define NB    64
#define NI    512
#define NH    1024
#define N3H   3072

// Coherent (agent-scope, cross-XCD) access helpers: per-access coherence,
// NO cache-wide fences (the round-2 killer: buffer_inv/wbl2 per step).
__device__ __forceinline__ u64 cload64(const u64* p) {
  return __hip_atomic_load(p, __ATOMIC_RELAXED, __HIP_MEMORY_SCOPE_AGENT);
}
__device__ __forceinline__ void cstore64(u64* p, u64 v) {
  __hip_atomic_store(p, v, __ATOMIC_RELAXED, __HIP_MEMORY_SCOPE_AGENT);
}
__device__ __forceinline__ void cstore32(unsigned* p, unsigned v) {
  __hip_atomic_store(p, v, __ATOMIC_RELAXED, __HIP_MEMORY_SCOPE_AGENT);
}

union H4 { u64 q; h16x4 v; };

// ============================================================
// Kernel 0: init h^(0) in FRAGMENT order, parity-0 plane.
// Fragment layout per bg-plane (32 KB): h16 idx = (kt*64 + l)*8 + j
// holding h[row = l&15][k = kt*32 + (l>>4)*8 + j].
// ============================================================
__global__ void gru_init_h(const float* __restrict__ hid0,
                           h16* __restrict__ hfrag) {
  int t = blockIdx.x * blockDim.x + threadIdx.x;   // 0..8191
  if (t >= 4 * 2048) return;
  int bg = t >> 11;
  int fl = t & 2047;                                // kt*64 + l
  int l  = fl & 63;
  int kbase = (fl >> 6) * 32 + (l >> 4) * 8;
  h16x8 v;
  #pragma unroll
  for (int j = 0; j < 8; ++j) v[j] = (h16)hid0[kbase + j];  // row-independent
  *(h16x8*)&hfrag[((size_t)bg * 2048 + fl) * 8] = v;        // parity 0 plane
}

// ============================================================
// Kernel 1: x = inp @ W_in + b  (f16 out, CONSUMER-TRANSPOSED layout)
// x layout: [t][gate][cg][bg][cc*16 + rr]  (512B block per (t,g,cg,bg))
// ============================================================
#define P1_BM 128
#define P1_BK 32

__device__ __forceinline__ int p1swz(int r, int k) {
  return r * P1_BK + ((((k >> 3) ^ (r & 3)) << 3) | (k & 7));
}

__global__ __launch_bounds__(256, 2) void gru_xgemm(
    const float* __restrict__ inp, const float* __restrict__ Win,
    const float* __restrict__ bstk, h16* __restrict__ x) {
  __shared__ h16 sAh[2][P1_BM * P1_BK];
  __shared__ h16 sAl[2][P1_BM * P1_BK];
  __shared__ h16 sBh[2][P1_BM * P1_BK];
  __shared__ h16 sBl[2][P1_BM * P1_BK];

  const int tid = threadIdx.x;
  const int l = tid & 63;
  const int w = tid >> 6;
  const int wm = (w >> 1) * 64, wn = (w & 1) * 64;
  const int mi = blockIdx.x, ni = blockIdx.y;

  const int sr  = tid >> 1;
  const int skh = (tid & 1) * 16;

  const float* aSrcBase = inp + (size_t)(sr & 63) * (T_SEQ * NI)
                              + (size_t)(mi * 2 + (sr >> 6)) * NI + skh;
  const float* bSrcBase = Win + (size_t)skh * N3H + ni * 128 + sr;

  f32x4 acc[4][4] = {};
  float aReg[16];
  float bReg[16];

  auto stage_load = [&](int ks) {
    const float* ap = aSrcBase + ks * P1_BK;
    #pragma unroll
    for (int jg = 0; jg < 4; ++jg) {
      f32x4 v = *(const f32x4*)(ap + jg * 4);
      aReg[jg*4+0] = v[0]; aReg[jg*4+1] = v[1];
      aReg[jg*4+2] = v[2]; aReg[jg*4+3] = v[3];
    }
    const float* bp = bSrcBase + (size_t)ks * P1_BK * N3H;
    #pragma unroll
    for (int j = 0; j < 16; ++j) bReg[j] = bp[(size_t)j * N3H];
  };

  auto stage_write = [&](int buf) {
    #pragma unroll
    for (int jg = 0; jg < 4; ++jg) {
      int idx = p1swz(sr, skh + jg * 4);
      h16x4 hi, lo;
      #pragma unroll
      for (int j = 0; j < 4; ++j) {
        float v = aReg[jg*4+j];
        h16 h = (h16)v; hi[j] = h; lo[j] = (h16)(v - (float)h);
      }
      *(h16x4*)&sAh[buf][idx] = hi;
      *(h16x4*)&sAl[buf][idx] = lo;
      #pragma unroll
      for (int j = 0; j < 4; ++j) {
        float v = bReg[jg*4+j];
        h16 h = (h16)v; hi[j] = h; lo[j] = (h16)(v - (float)h);
      }
      *(h16x4*)&sBh[buf][idx] = hi;
      *(h16x4*)&sBl[buf][idx] = lo;
    }
  };

  auto compute = [&](int buf) {
    const int k0 = (l >> 4) * 8;
    h16x8 bh[4], bl[4];
    #pragma unroll
    for (int nt = 0; nt < 4; ++nt) {
      int idx = p1swz(wn + nt * 16 + (l & 15), k0);
      bh[nt] = *(const h16x8*)&sBh[buf][idx];
      bl[nt] = *(const h16x8*)&sBl[buf][idx];
    }
    #pragma unroll
    for (int mt = 0; mt < 4; ++mt) {
      int idx = p1swz(wm + mt * 16 + (l & 15), k0);
      h16x8 ah = *(const h16x8*)&sAh[buf][idx];
      h16x8 al = *(const h16x8*)&sAl[buf][idx];
      #pragma unroll
      for (int nt = 0; nt < 4; ++nt) {
        acc[mt][nt] = __builtin_amdgcn_mfma_f32_16x16x32_f16(ah, bh[nt], acc[mt][nt], 0, 0, 0);
        acc[mt][nt] = __builtin_amdgcn_mfma_f32_16x16x32_f16(ah, bl[nt], acc[mt][nt], 0, 0, 0);
        acc[mt][nt] = __builtin_amdgcn_mfma_f32_16x16x32_f16(al, bh[nt], acc[mt][nt], 0, 0, 0);
      }
    }
  };

  stage_load(0);
  stage_write(0);
  __syncthreads();
  for (int ks = 0; ks < 16; ++ks) {
    int buf = ks & 1;
    if (ks < 15) stage_load(ks + 1);
    compute(buf);
    if (ks < 15) stage_write(buf ^ 1);
    __syncthreads();
  }

  const int t = mi * 2 + (wm >> 6);
  const int rrb = (l >> 4) * 4;
  #pragma unroll
  for (int nt = 0; nt < 4; ++nt) {
    int colhi = ni * 8 + (wn >> 4) + nt;
    int gg  = colhi >> 6;
    int cgx = colhi & 63;
    float bias = bstk[(colhi << 4) + (l & 15)];
    #pragma unroll
    for (int mt = 0; mt < 4; ++mt) {
      h16x4 v;
      #pragma unroll
      for (int i = 0; i < 4; ++i) v[i] = (h16)(acc[mt][nt][i] + bias);
      size_t idx = ((((size_t)t * 3 + gg) * 64 + cgx) * 4 + mt) * 256
                 + (size_t)(l & 15) * 16 + rrb;
      *(h16x4*)&x[idx] = v;
    }
  }
}

// ============================================================
// Kernel 2: persistent GRU recurrence, single-f16 h, fragment-order
// h exchange. 256 WG = 64 cg x 4 bg, 3 waves (one gate each), 1 WG/CU.
// Per step: spin -> linear 32KB coherent copy to LDS -> b1 ->
// 32x{ds_read_b128 A,B + MFMA} -> gates -> b2 -> wave2: tanh, LDS
// transpose, ONE coalesced cstore64/lane, vmcnt(0), flag.
// ============================================================
__global__ __launch_bounds__(192, 1) void gru_steps(
    const float* __restrict__ Whid,   // [1024][3072] f32
    const h16* __restrict__ x,        // transposed layout, f16
    h16* __restrict__ hfrag,          // [2 parity][4 bg][16384] f16 frag-order
    unsigned* __restrict__ flags,     // [64 cg][4 bg]
    const float* __restrict__ hid0,   // [1024]
    float* __restrict__ out) {        // [64][1024] f32
  __shared__ h16 U[3 * 32 * 64 * 8];  // 96 KiB fragment-ordered W_hid slice
  __shared__ h16 hstage[16384];       // 32 KiB staged h plane (frag order)
  __shared__ float rbuf[2][16 * 17];
  __shared__ float ubuf[2][16 * 17];  // parity-dbuf'd r/u exchange
  __shared__ h16 tbuf[16 * 20];       // wave2 store-transpose staging

  const int tid = threadIdx.x;
  const int l = tid & 63;
  const int g = tid >> 6;
  const int cg = blockIdx.x & 63;
  const int bg = blockIdx.x >> 6;

  // ---- one-time: W_hid slice -> fragment-ordered LDS ----
  {
    const float* base = Whid + (size_t)g * NH + (size_t)cg * 16 + (l & 15);
    for (int kt = 0; kt < 32; ++kt) {
      const float* src = base + (size_t)(kt * 32 + (l >> 4) * 8) * N3H;
      h16x8 v;
      #pragma unroll
      for (int j = 0; j < 8; ++j) v[j] = (h16)src[(size_t)j * N3H];
      *(h16x8*)&U[(size_t)((g * 32 + kt) * 64 + l) * 8] = v;
    }
  }

  const int rr0 = (l >> 4) * 4, cc = l & 15;

  // ---- wave2: persistent f32 h_prev registers (owner-only tile) ----
  float hq[4];
  if (g == 2) {
    float h0 = hid0[cg * 16 + cc];    // broadcast over batch rows
    #pragma unroll
    for (int i = 0; i < 4; ++i) hq[i] = h0;
  }
  __syncthreads();

  // x pointer for this wave (one 8B load per step)
  const char* xb = (const char*)(x
      + ((((size_t)g * 64 + cg) * 4 + bg) * 256)
      + (size_t)cc * 16 + rr0);
  u64 xq = *(const u64*)xb;   // step-1 tile, prefetched

  const h16* Ug = &U[(size_t)g * 32 * 64 * 8];
  u64* hfU64 = (u64*)hfrag;

  for (int s = 1; s <= T_SEQ; ++s) {
    // ---- spin: all 64 cg of our bg done with step s-1 ----
    const unsigned tgt = (unsigned)(s - 1);
    int spincnt = 0;
    for (;;) {
      unsigned v = __hip_atomic_load(&flags[l * 4 + bg], __ATOMIC_RELAXED,
                                     __HIP_MEMORY_SCOPE_AGENT);
      if (__all((int)(v >= tgt))) break;
      __builtin_amdgcn_s_sleep(1);
      if (++spincnt > 30000) break;   // hang-safety
    }
    __builtin_amdgcn_sched_barrier(0);

    // ---- linear coherent copy: h frag plane (4096 u64) -> LDS ----
    const u64* src = hfU64 + ((size_t)((s - 1) & 1) * 4 + bg) * 2048 * 2;
    u64 tmp[22];
    #pragma unroll
    for (int k = 0; k < 22; ++k) {
      int wd = tid + 192 * k;
      tmp[k] = (wd < 4096) ? cload64(src + wd) : 0;
    }
    #pragma unroll
    for (int k = 0; k < 22; ++k) {
      int wd = tid + 192 * k;
      if (wd < 4096) ((u64*)hstage)[wd] = tmp[k];
    }
    // prefetch next step's x tile (plain cached load)
    u64 xq_next = xq;
    if (s < T_SEQ) xq_next = *(const u64*)(xb + (size_t)s * 393216);
    __syncthreads();   // b1: h staged

    // ---- hid = h_f16 @ U_gate : 32 MFMA, contiguous b128 reads ----
    f32x4 a0 = {}, a1 = {};
    #pragma unroll
    for (int kt = 0; kt < 32; ++kt) {
      h16x8 a = *(const h16x8*)&hstage[(kt * 64 + l) * 8];
      h16x8 b = *(const h16x8*)&Ug[(kt * 64 + l) * 8];
      if (kt & 1) a1 = __builtin_amdgcn_mfma_f32_16x16x32_f16(a, b, a1, 0, 0, 0);
      else        a0 = __builtin_amdgcn_mfma_f32_16x16x32_f16(a, b, a0, 0, 0, 0);
    }
    f32x4 hid;
    #pragma unroll
    for (int i = 0; i < 4; ++i) hid[i] = a0[i] + a1[i];

    H4 xc; xc.q = xq;
    const int p = s & 1;

    if (g == 0) {
      #pragma unroll
      for (int i = 0; i < 4; ++i) {
        float pr = (float)xc.v[i] + hid[i];
        rbuf[p][(rr0 + i) * 17 + cc] = 1.0f / (1.0f + __expf(-pr));
      }
    } else if (g == 1) {
      #pragma unroll
      for (int i = 0; i < 4; ++i) {
        float pu = (float)xc.v[i] + hid[i];
        ubuf[p][(rr0 + i) * 17 + cc] = 1.0f / (1.0f + __expf(-pu));
      }
    }
    __syncthreads();   // b2: r,u visible to wave 2

    if (g == 2) {
      #pragma unroll
      for (int i = 0; i < 4; ++i) {
        int rr = rr0 + i;
        float r = rbuf[p][rr * 17 + cc];
        float u = ubuf[p][rr * 17 + cc];
        float c = tanhf((float)xc.v[i] + r * hid[i]);
        float hn = (1.0f - u) * hq[i] + u * c;
        hq[i] = hn;
        tbuf[rr * 20 + cc] = (h16)hn;
        if (s == T_SEQ) out[(size_t)(bg * 16 + rr) * NH + cg * 16 + cc] = hn;
      }
      // in-wave transpose: lane l -> contiguous u64 of the 512B frag block
      u64 blk = *(const u64*)&tbuf[((l >> 1) & 15) * 20
                                   + (l >> 5) * 8 + (l & 1) * 4];
      u64* dst = hfU64 + (((size_t)(s & 1) * 4 + bg) * 4096) + cg * 64 + l;
      cstore64(dst, blk);
      asm volatile("s_waitcnt vmcnt(0)" ::: "memory");   // h at coherence point
      if (l == 0) cstore32(&flags[cg * 4 + bg], (unsigned)s);
    }
    xq = xq_next;
  }
}

// ============================================================
extern "C" void kernel_launch(void* const* d_in, const int* in_sizes, int n_in,
                              void* d_out, int out_size, void* d_ws, size_t ws_size,
                              hipStream_t stream) {
  const float* inp  = (const float*)d_in[0];
  const float* Win  = (const float*)d_in[1];
  const float* Whid = (const float*)d_in[2];
  const float* bstk = (const float*)d_in[3];
  const float* hid0 = (const float*)d_in[4];
  float* out = (float*)d_out;

  char* ws = (char*)d_ws;
  const size_t xBytes = (size_t)T_SEQ * NB * N3H * sizeof(h16);   // 201,326,592
  const size_t hBytes = (size_t)2 * 4 * 16384 * sizeof(h16);      //     262,144
  const size_t fBytes = 64 * 4 * sizeof(unsigned);                //       1,024
  if (ws_size < xBytes + hBytes + fBytes) return;

  h16* x = (h16*)ws;
  h16* hfrag = (h16*)(ws + xBytes);
  unsigned* flags = (unsigned*)(ws + xBytes + hBytes);

  hipMemsetAsync(flags, 0, fBytes, stream);

  gru_init_h<<<dim3(8192 / 256), dim3(256), 0, stream>>>(hid0, hfrag);

  dim3 g1(32768 / P1_BM, N3H / 128);
  gru_xgemm<<<g1, dim3(256), 0, stream>>>(inp, Win, bstk, x);

  gru_steps<<<dim3(256), dim3(192), 0, stream>>>(Whid, x, hfrag, flags, hid0, out);
}

// Round 6
// 2729.768 us; speedup vs baseline: 5.4861x; 1.4310x over previous
//
#include <hip/hip_runtime.h>
#include <hip/hip_fp16.h>

typedef _Float16 h16;
typedef __attribute__((ext_vector_type(4))) _Float16 h16x4;
typedef __attribute__((ext_vector_type(8))) _Float16 h16x8;
typedef __attribute__((ext_vector_type(4))) float f32x4;
typedef unsigned long long u64;

#define T_SEQ 512
#define NB    64
#define NI    512
#define NH    1024
#define N3H   3072

// Coherent (agent-scope, cross-XCD) access helpers: per-access coherence,
// NO cache-wide fences (the round-2 killer: buffer_inv/wbl2 per step).
__device__ __forceinline__ u64 cload64(const u64* p) {
  return __hip_atomic_load(p, __ATOMIC_RELAXED, __HIP_MEMORY_SCOPE_AGENT);
}
__device__ __forceinline__ void cstore64(u64* p, u64 v) {
  __hip_atomic_store(p, v, __ATOMIC_RELAXED, __HIP_MEMORY_SCOPE_AGENT);
}

union H4 { u64 q; h16x4 v; };

// ============================================================
// Kernel 0: init h^(0) in FRAGMENT order, parity-0 plane.
// Fragment layout per bg-plane (32 KB): h16 idx = (kt*64 + l)*8 + j
// holding h[row = l&15][k = kt*32 + (l>>4)*8 + j].
// ============================================================
__global__ void gru_init_h(const float* __restrict__ hid0,
                           h16* __restrict__ hfrag) {
  int t = blockIdx.x * blockDim.x + threadIdx.x;   // 0..8191
  if (t >= 4 * 2048) return;
  int bg = t >> 11;
  int fl = t & 2047;                                // kt*64 + l
  int l  = fl & 63;
  int kbase = (fl >> 6) * 32 + (l >> 4) * 8;
  h16x8 v;
  #pragma unroll
  for (int j = 0; j < 8; ++j) v[j] = (h16)hid0[kbase + j];  // row-independent
  *(h16x8*)&hfrag[((size_t)bg * 2048 + fl) * 8] = v;        // parity 0 plane
}

// ============================================================
// Kernel 1: x = inp @ W_in + b  (f16 out, CONSUMER-TRANSPOSED layout)
// x layout: [t][gate][cg][bg][cc*16 + rr]  (512B block per (t,g,cg,bg))
// ============================================================
#define P1_BM 128
#define P1_BK 32

__device__ __forceinline__ int p1swz(int r, int k) {
  return r * P1_BK + ((((k >> 3) ^ (r & 3)) << 3) | (k & 7));
}

__global__ __launch_bounds__(256, 2) void gru_xgemm(
    const float* __restrict__ inp, const float* __restrict__ Win,
    const float* __restrict__ bstk, h16* __restrict__ x) {
  __shared__ h16 sAh[2][P1_BM * P1_BK];
  __shared__ h16 sAl[2][P1_BM * P1_BK];
  __shared__ h16 sBh[2][P1_BM * P1_BK];
  __shared__ h16 sBl[2][P1_BM * P1_BK];

  const int tid = threadIdx.x;
  const int l = tid & 63;
  const int w = tid >> 6;
  const int wm = (w >> 1) * 64, wn = (w & 1) * 64;
  const int mi = blockIdx.x, ni = blockIdx.y;

  const int sr  = tid >> 1;
  const int skh = (tid & 1) * 16;

  const float* aSrcBase = inp + (size_t)(sr & 63) * (T_SEQ * NI)
                              + (size_t)(mi * 2 + (sr >> 6)) * NI + skh;
  const float* bSrcBase = Win + (size_t)skh * N3H + ni * 128 + sr;

  f32x4 acc[4][4] = {};
  float aReg[16];
  float bReg[16];

  auto stage_load = [&](int ks) {
    const float* ap = aSrcBase + ks * P1_BK;
    #pragma unroll
    for (int jg = 0; jg < 4; ++jg) {
      f32x4 v = *(const f32x4*)(ap + jg * 4);
      aReg[jg*4+0] = v[0]; aReg[jg*4+1] = v[1];
      aReg[jg*4+2] = v[2]; aReg[jg*4+3] = v[3];
    }
    const float* bp = bSrcBase + (size_t)ks * P1_BK * N3H;
    #pragma unroll
    for (int j = 0; j < 16; ++j) bReg[j] = bp[(size_t)j * N3H];
  };

  auto stage_write = [&](int buf) {
    #pragma unroll
    for (int jg = 0; jg < 4; ++jg) {
      int idx = p1swz(sr, skh + jg * 4);
      h16x4 hi, lo;
      #pragma unroll
      for (int j = 0; j < 4; ++j) {
        float v = aReg[jg*4+j];
        h16 h = (h16)v; hi[j] = h; lo[j] = (h16)(v - (float)h);
      }
      *(h16x4*)&sAh[buf][idx] = hi;
      *(h16x4*)&sAl[buf][idx] = lo;
      #pragma unroll
      for (int j = 0; j < 4; ++j) {
        float v = bReg[jg*4+j];
        h16 h = (h16)v; hi[j] = h; lo[j] = (h16)(v - (float)h);
      }
      *(h16x4*)&sBh[buf][idx] = hi;
      *(h16x4*)&sBl[buf][idx] = lo;
    }
  };

  auto compute = [&](int buf) {
    const int k0 = (l >> 4) * 8;
    h16x8 bh[4], bl[4];
    #pragma unroll
    for (int nt = 0; nt < 4; ++nt) {
      int idx = p1swz(wn + nt * 16 + (l & 15), k0);
      bh[nt] = *(const h16x8*)&sBh[buf][idx];
      bl[nt] = *(const h16x8*)&sBl[buf][idx];
    }
    #pragma unroll
    for (int mt = 0; mt < 4; ++mt) {
      int idx = p1swz(wm + mt * 16 + (l & 15), k0);
      h16x8 ah = *(const h16x8*)&sAh[buf][idx];
      h16x8 al = *(const h16x8*)&sAl[buf][idx];
      #pragma unroll
      for (int nt = 0; nt < 4; ++nt) {
        acc[mt][nt] = __builtin_amdgcn_mfma_f32_16x16x32_f16(ah, bh[nt], acc[mt][nt], 0, 0, 0);
        acc[mt][nt] = __builtin_amdgcn_mfma_f32_16x16x32_f16(ah, bl[nt], acc[mt][nt], 0, 0, 0);
        acc[mt][nt] = __builtin_amdgcn_mfma_f32_16x16x32_f16(al, bh[nt], acc[mt][nt], 0, 0, 0);
      }
    }
  };

  stage_load(0);
  stage_write(0);
  __syncthreads();
  for (int ks = 0; ks < 16; ++ks) {
    int buf = ks & 1;
    if (ks < 15) stage_load(ks + 1);
    compute(buf);
    if (ks < 15) stage_write(buf ^ 1);
    __syncthreads();
  }

  const int t = mi * 2 + (wm >> 6);
  const int rrb = (l >> 4) * 4;
  #pragma unroll
  for (int nt = 0; nt < 4; ++nt) {
    int colhi = ni * 8 + (wn >> 4) + nt;
    int gg  = colhi >> 6;
    int cgx = colhi & 63;
    float bias = bstk[(colhi << 4) + (l & 15)];
    #pragma unroll
    for (int mt = 0; mt < 4; ++mt) {
      h16x4 v;
      #pragma unroll
      for (int i = 0; i < 4; ++i) v[i] = (h16)(acc[mt][nt][i] + bias);
      size_t idx = ((((size_t)t * 3 + gg) * 64 + cgx) * 4 + mt) * 256
                 + (size_t)(l & 15) * 16 + rrb;
      *(h16x4*)&x[idx] = v;
    }
  }
}

// ============================================================
// Kernel 2: persistent GRU recurrence, single-f16 h, fragment-order
// h exchange, SINGLE AGGREGATED COUNTER per bg-ring (kills the
// round-5 poll storm: 1 line polled instead of 16).
// ============================================================
__global__ __launch_bounds__(192, 1) void gru_steps(
    const float* __restrict__ Whid,   // [1024][3072] f32
    const h16* __restrict__ x,        // transposed layout, f16
    h16* __restrict__ hfrag,          // [2 parity][4 bg][16384] f16 frag-order
    unsigned* __restrict__ cnt,       // [4 bg] counters, 128B apart
    const float* __restrict__ hid0,   // [1024]
    float* __restrict__ out) {        // [64][1024] f32
  __shared__ h16 U[3 * 32 * 64 * 8];  // 96 KiB fragment-ordered W_hid slice
  __shared__ h16 hstage[16384];       // 32 KiB staged h plane (frag order)
  __shared__ float rbuf[2][16 * 17];
  __shared__ float ubuf[2][16 * 17];  // parity-dbuf'd r/u exchange
  __shared__ h16 tbuf[16 * 20];       // wave2 store-transpose staging

  const int tid = threadIdx.x;
  const int l = tid & 63;
  const int g = tid >> 6;
  const int cg = blockIdx.x & 63;
  const int bg = blockIdx.x >> 6;

  // ---- one-time: W_hid slice -> fragment-ordered LDS ----
  {
    const float* base = Whid + (size_t)g * NH + (size_t)cg * 16 + (l & 15);
    for (int kt = 0; kt < 32; ++kt) {
      const float* src = base + (size_t)(kt * 32 + (l >> 4) * 8) * N3H;
      h16x8 v;
      #pragma unroll
      for (int j = 0; j < 8; ++j) v[j] = (h16)src[(size_t)j * N3H];
      *(h16x8*)&U[(size_t)((g * 32 + kt) * 64 + l) * 8] = v;
    }
  }

  const int rr0 = (l >> 4) * 4, cc = l & 15;

  // ---- wave2: persistent f32 h_prev registers (owner-only tile) ----
  float hq[4];
  if (g == 2) {
    float h0 = hid0[cg * 16 + cc];    // broadcast over batch rows
    #pragma unroll
    for (int i = 0; i < 4; ++i) hq[i] = h0;
  }
  __syncthreads();

  // x pointer for this wave (one 8B load per step)
  const char* xb = (const char*)(x
      + ((((size_t)g * 64 + cg) * 4 + bg) * 256)
      + (size_t)cc * 16 + rr0);
  u64 xq = *(const u64*)xb;   // step-1 tile, prefetched

  const h16* Ug = &U[(size_t)g * 32 * 64 * 8];
  u64* hfU64 = (u64*)hfrag;
  unsigned* mycnt = cnt + bg * 32;   // 128B-separated counter per ring

  for (int s = 1; s <= T_SEQ; ++s) {
    // ---- spin: ring counter reaches 64*(s-1)  (ONE line, all lanes) ----
    const unsigned need = 64u * (unsigned)(s - 1);
    int spincnt = 0;
    for (;;) {
      unsigned v = __hip_atomic_load(mycnt, __ATOMIC_RELAXED,
                                     __HIP_MEMORY_SCOPE_AGENT);
      if (__builtin_amdgcn_readfirstlane(v) >= need) break;
      __builtin_amdgcn_s_sleep(1);
      if (++spincnt > 200000) break;   // hang-safety
    }
    __builtin_amdgcn_sched_barrier(0);

    // prefetch next step's x tile first (plain cached load, independent)
    u64 xq_next = xq;
    if (s < T_SEQ) xq_next = *(const u64*)(xb + (size_t)s * 393216);

    // ---- linear coherent copy: h frag plane (4096 u64) -> LDS ----
    const u64* src = hfU64 + ((size_t)((s - 1) & 1) * 4 + bg) * 4096;
    u64 tmp[22];
    #pragma unroll
    for (int k = 0; k < 22; ++k) {
      int wd = tid + 192 * k;
      tmp[k] = (wd < 4096) ? cload64(src + wd) : 0;
    }
    #pragma unroll
    for (int k = 0; k < 22; ++k) {
      int wd = tid + 192 * k;
      if (wd < 4096) ((u64*)hstage)[wd] = tmp[k];
    }
    __syncthreads();   // b1: h staged

    // ---- hid = h_f16 @ U_gate : 32 MFMA, contiguous b128 reads ----
    f32x4 a0 = {}, a1 = {};
    #pragma unroll
    for (int kt = 0; kt < 32; ++kt) {
      h16x8 a = *(const h16x8*)&hstage[(kt * 64 + l) * 8];
      h16x8 b = *(const h16x8*)&Ug[(kt * 64 + l) * 8];
      if (kt & 1) a1 = __builtin_amdgcn_mfma_f32_16x16x32_f16(a, b, a1, 0, 0, 0);
      else        a0 = __builtin_amdgcn_mfma_f32_16x16x32_f16(a, b, a0, 0, 0, 0);
    }
    f32x4 hid;
    #pragma unroll
    for (int i = 0; i < 4; ++i) hid[i] = a0[i] + a1[i];

    H4 xc; xc.q = xq;
    const int p = s & 1;

    if (g == 0) {
      #pragma unroll
      for (int i = 0; i < 4; ++i) {
        float pr = (float)xc.v[i] + hid[i];
        rbuf[p][(rr0 + i) * 17 + cc] = 1.0f / (1.0f + __expf(-pr));
      }
    } else if (g == 1) {
      #pragma unroll
      for (int i = 0; i < 4; ++i) {
        float pu = (float)xc.v[i] + hid[i];
        ubuf[p][(rr0 + i) * 17 + cc] = 1.0f / (1.0f + __expf(-pu));
      }
    }
    __syncthreads();   // b2: r,u visible to wave 2

    if (g == 2) {
      #pragma unroll
      for (int i = 0; i < 4; ++i) {
        int rr = rr0 + i;
        float r = rbuf[p][rr * 17 + cc];
        float u = ubuf[p][rr * 17 + cc];
        float c = tanhf((float)xc.v[i] + r * hid[i]);
        float hn = (1.0f - u) * hq[i] + u * c;
        hq[i] = hn;
        tbuf[rr * 20 + cc] = (h16)hn;
        if (s == T_SEQ) out[(size_t)(bg * 16 + rr) * NH + cg * 16 + cc] = hn;
      }
      // in-wave transpose: lane l -> contiguous u64 of the 512B frag block
      u64 blk = *(const u64*)&tbuf[((l >> 1) & 15) * 20
                                   + (l >> 5) * 8 + (l & 1) * 4];
      u64* dst = hfU64 + (((size_t)(s & 1) * 4 + bg) * 4096) + cg * 64 + l;
      cstore64(dst, blk);
      asm volatile("s_waitcnt vmcnt(0)" ::: "memory");   // h at coherence point
      if (l == 0)
        (void)__hip_atomic_fetch_add(mycnt, 1u, __ATOMIC_RELAXED,
                                     __HIP_MEMORY_SCOPE_AGENT);
    }
    xq = xq_next;
  }
}

// ============================================================
extern "C" void kernel_launch(void* const* d_in, const int* in_sizes, int n_in,
                              void* d_out, int out_size, void* d_ws, size_t ws_size,
                              hipStream_t stream) {
  const float* inp  = (const float*)d_in[0];
  const float* Win  = (const float*)d_in[1];
  const float* Whid = (const float*)d_in[2];
  const float* bstk = (const float*)d_in[3];
  const float* hid0 = (const float*)d_in[4];
  float* out = (float*)d_out;

  char* ws = (char*)d_ws;
  const size_t xBytes = (size_t)T_SEQ * NB * N3H * sizeof(h16);   // 201,326,592
  const size_t hBytes = (size_t)2 * 4 * 16384 * sizeof(h16);      //     262,144
  const size_t cBytes = 4 * 32 * sizeof(unsigned);                //         512
  if (ws_size < xBytes + hBytes + cBytes) return;

  h16* x = (h16*)ws;
  h16* hfrag = (h16*)(ws + xBytes);
  unsigned* cnt = (unsigned*)(ws + xBytes + hBytes);

  hipMemsetAsync(cnt, 0, cBytes, stream);

  gru_init_h<<<dim3(8192 / 256), dim3(256), 0, stream>>>(hid0, hfrag);

  dim3 g1(32768 / P1_BM, N3H / 128);
  gru_xgemm<<<g1, dim3(256), 0, stream>>>(inp, Win, bstk, x);

  gru_steps<<<dim3(256), dim3(192), 0, stream>>>(Whid, x, hfrag, cnt, hid0, out);
}

// Round 7
// 2620.192 us; speedup vs baseline: 5.7155x; 1.0418x over previous
//
#include <hip/hip_runtime.h>
#include <hip/hip_fp16.h>
#include <math.h>

typedef _Float16 h16;
typedef __attribute__((ext_vector_type(4))) _Float16 h16x4;
typedef __attribute__((ext_vector_type(8))) _Float16 h16x8;
typedef __attribute__((ext_vector_type(4))) float f32x4;
typedef unsigned long long u64;

#define T_SEQ 512
#define NB    64
#define NI    512
#define NH    1024
#define N3H   3072

// Agent-scope (cross-XCD coherent point) access helpers. Relaxed per-access
// coherence only — NO cache-wide fences, NO flags, NO counters: the h words
// are SELF-VALIDATING (14-bit fixed-point pairs + 4-bit epoch tag per u32).
__device__ __forceinline__ u64 cload64(const u64* p) {
  return __hip_atomic_load(p, __ATOMIC_RELAXED, __HIP_MEMORY_SCOPE_AGENT);
}
__device__ __forceinline__ void cstore64(u64* p, u64 v) {
  __hip_atomic_store(p, v, __ATOMIC_RELAXED, __HIP_MEMORY_SCOPE_AGENT);
}

union H4 { u64 q; h16x4 v; };

// h word format (u64 = 4 h-values of one row, 4 consecutive cols):
//   lo u32: q0[0:14) | q1[14:28) | tag[28:32)     q = rint(h*8192), 14-bit 2c
//   hi u32: q2[0:14) | q3[14:28) | 0
// tag = (producing_step >> 1) & 15  (epoch of this parity plane).

// ============================================================
// Kernel 0: init h^(0) plane (parity 0) in packed-frag order, tag 0.
// word w: bg=w>>12, cg=(w&4095)>>6, l=w&63; cols cg*16+(l>>5)*8+(l&1)*4.
// ============================================================
__global__ void gru_init_h(const float* __restrict__ hid0,
                           u64* __restrict__ hfrag) {
  int w = blockIdx.x * blockDim.x + threadIdx.x;   // 0..16383
  if (w >= 16384) return;
  int l  = w & 63;
  int cg = (w & 4095) >> 6;
  int cb = cg * 16 + ((l >> 5) << 3) + ((l & 1) << 2);
  unsigned q[4];
  #pragma unroll
  for (int j = 0; j < 4; ++j) {
    float v = fminf(fmaxf(hid0[cb + j] * 8192.0f, -8192.0f), 8191.0f);
    q[j] = (unsigned)((int)__builtin_rintf(v)) & 0x3FFFu;
  }
  unsigned lo = q[0] | (q[1] << 14);               // tag = 0
  unsigned hi = q[2] | (q[3] << 14);
  hfrag[w] = (u64)lo | ((u64)hi << 32);
}

// ============================================================
// Kernel 1: x = inp @ W_in + b  (f16 out, CONSUMER-TRANSPOSED layout)
// x layout: [t][gate][cg][bg][cc*16 + rr]  (512B block per (t,g,cg,bg))
// ============================================================
#define P1_BM 128
#define P1_BK 32

__device__ __forceinline__ int p1swz(int r, int k) {
  return r * P1_BK + ((((k >> 3) ^ (r & 3)) << 3) | (k & 7));
}

__global__ __launch_bounds__(256, 2) void gru_xgemm(
    const float* __restrict__ inp, const float* __restrict__ Win,
    const float* __restrict__ bstk, h16* __restrict__ x) {
  __shared__ h16 sAh[2][P1_BM * P1_BK];
  __shared__ h16 sAl[2][P1_BM * P1_BK];
  __shared__ h16 sBh[2][P1_BM * P1_BK];
  __shared__ h16 sBl[2][P1_BM * P1_BK];

  const int tid = threadIdx.x;
  const int l = tid & 63;
  const int w = tid >> 6;
  const int wm = (w >> 1) * 64, wn = (w & 1) * 64;
  const int mi = blockIdx.x, ni = blockIdx.y;

  const int sr  = tid >> 1;
  const int skh = (tid & 1) * 16;

  const float* aSrcBase = inp + (size_t)(sr & 63) * (T_SEQ * NI)
                              + (size_t)(mi * 2 + (sr >> 6)) * NI + skh;
  const float* bSrcBase = Win + (size_t)skh * N3H + ni * 128 + sr;

  f32x4 acc[4][4] = {};
  float aReg[16];
  float bReg[16];

  auto stage_load = [&](int ks) {
    const float* ap = aSrcBase + ks * P1_BK;
    #pragma unroll
    for (int jg = 0; jg < 4; ++jg) {
      f32x4 v = *(const f32x4*)(ap + jg * 4);
      aReg[jg*4+0] = v[0]; aReg[jg*4+1] = v[1];
      aReg[jg*4+2] = v[2]; aReg[jg*4+3] = v[3];
    }
    const float* bp = bSrcBase + (size_t)ks * P1_BK * N3H;
    #pragma unroll
    for (int j = 0; j < 16; ++j) bReg[j] = bp[(size_t)j * N3H];
  };

  auto stage_write = [&](int buf) {
    #pragma unroll
    for (int jg = 0; jg < 4; ++jg) {
      int idx = p1swz(sr, skh + jg * 4);
      h16x4 hi, lo;
      #pragma unroll
      for (int j = 0; j < 4; ++j) {
        float v = aReg[jg*4+j];
        h16 h = (h16)v; hi[j] = h; lo[j] = (h16)(v - (float)h);
      }
      *(h16x4*)&sAh[buf][idx] = hi;
      *(h16x4*)&sAl[buf][idx] = lo;
      #pragma unroll
      for (int j = 0; j < 4; ++j) {
        float v = bReg[jg*4+j];
        h16 h = (h16)v; hi[j] = h; lo[j] = (h16)(v - (float)h);
      }
      *(h16x4*)&sBh[buf][idx] = hi;
      *(h16x4*)&sBl[buf][idx] = lo;
    }
  };

  auto compute = [&](int buf) {
    const int k0 = (l >> 4) * 8;
    h16x8 bh[4], bl[4];
    #pragma unroll
    for (int nt = 0; nt < 4; ++nt) {
      int idx = p1swz(wn + nt * 16 + (l & 15), k0);
      bh[nt] = *(const h16x8*)&sBh[buf][idx];
      bl[nt] = *(const h16x8*)&sBl[buf][idx];
    }
    #pragma unroll
    for (int mt = 0; mt < 4; ++mt) {
      int idx = p1swz(wm + mt * 16 + (l & 15), k0);
      h16x8 ah = *(const h16x8*)&sAh[buf][idx];
      h16x8 al = *(const h16x8*)&sAl[buf][idx];
      #pragma unroll
      for (int nt = 0; nt < 4; ++nt) {
        acc[mt][nt] = __builtin_amdgcn_mfma_f32_16x16x32_f16(ah, bh[nt], acc[mt][nt], 0, 0, 0);
        acc[mt][nt] = __builtin_amdgcn_mfma_f32_16x16x32_f16(ah, bl[nt], acc[mt][nt], 0, 0, 0);
        acc[mt][nt] = __builtin_amdgcn_mfma_f32_16x16x32_f16(al, bh[nt], acc[mt][nt], 0, 0, 0);
      }
    }
  };

  stage_load(0);
  stage_write(0);
  __syncthreads();
  for (int ks = 0; ks < 16; ++ks) {
    int buf = ks & 1;
    if (ks < 15) stage_load(ks + 1);
    compute(buf);
    if (ks < 15) stage_write(buf ^ 1);
    __syncthreads();
  }

  const int t = mi * 2 + (wm >> 6);
  const int rrb = (l >> 4) * 4;
  #pragma unroll
  for (int nt = 0; nt < 4; ++nt) {
    int colhi = ni * 8 + (wn >> 4) + nt;
    int gg  = colhi >> 6;
    int cgx = colhi & 63;
    float bias = bstk[(colhi << 4) + (l & 15)];
    #pragma unroll
    for (int mt = 0; mt < 4; ++mt) {
      h16x4 v;
      #pragma unroll
      for (int i = 0; i < 4; ++i) v[i] = (h16)(acc[mt][nt][i] + bias);
      size_t idx = ((((size_t)t * 3 + gg) * 64 + cgx) * 4 + mt) * 256
                 + (size_t)(l & 15) * 16 + rrb;
      *(h16x4*)&x[idx] = v;
    }
  }
}

// ============================================================
// Kernel 2: persistent GRU recurrence, SELF-VALIDATING h exchange.
// 256 WG = 64 cg x 4 bg, 3 waves (one gate each), 1 WG/CU.
// Per step: load h words (retry stale tags per-lane) -> unpack to f16
// frag in LDS -> b1 -> 32 MFMA -> gates -> b2 -> wave2: pack+store.
// No drain, no counters, no flags: 1 LLC hop of sync per step.
// ============================================================
__global__ __launch_bounds__(192, 1) void gru_steps(
    const float* __restrict__ Whid,   // [1024][3072] f32
    const h16* __restrict__ x,        // transposed layout, f16
    u64* __restrict__ hfrag,          // [2 parity][4 bg][4096] u64 packed
    const float* __restrict__ hid0,   // [1024]
    float* __restrict__ out) {        // [64][1024] f32
  __shared__ h16 U[3 * 32 * 64 * 8];  // 96 KiB fragment-ordered W_hid slice
  __shared__ h16 hstage[16384];       // 32 KiB unpacked h plane (frag order)
  __shared__ float rbuf[2][16 * 17];
  __shared__ float ubuf[2][16 * 17];  // parity-dbuf'd r/u exchange
  __shared__ unsigned short tq[16 * 20];  // wave2 store-transpose staging (q14)

  const int tid = threadIdx.x;
  const int l = tid & 63;
  const int g = tid >> 6;
  const int cg = blockIdx.x & 63;
  const int bg = blockIdx.x >> 6;

  // ---- one-time: W_hid slice -> fragment-ordered LDS ----
  {
    const float* base = Whid + (size_t)g * NH + (size_t)cg * 16 + (l & 15);
    for (int kt = 0; kt < 32; ++kt) {
      const float* src = base + (size_t)(kt * 32 + (l >> 4) * 8) * N3H;
      h16x8 v;
      #pragma unroll
      for (int j = 0; j < 8; ++j) v[j] = (h16)src[(size_t)j * N3H];
      *(h16x8*)&U[(size_t)((g * 32 + kt) * 64 + l) * 8] = v;
    }
  }

  const int rr0 = (l >> 4) * 4, cc = l & 15;

  // ---- wave2: persistent f32 h_prev registers (owner-only tile) ----
  float hq[4];
  if (g == 2) {
    float h0 = hid0[cg * 16 + cc];    // broadcast over batch rows
    #pragma unroll
    for (int i = 0; i < 4; ++i) hq[i] = h0;
  }
  __syncthreads();

  // x pointer for this wave (one 8B load per step)
  const char* xb = (const char*)(x
      + ((((size_t)g * 64 + cg) * 4 + bg) * 256)
      + (size_t)cc * 16 + rr0);
  u64 xq = *(const u64*)xb;   // step-1 tile, prefetched

  const h16* Ug = &U[(size_t)g * 32 * 64 * 8];
  const float S = 1.0f / 8192.0f;

  for (int s = 1; s <= T_SEQ; ++s) {
    // prefetch next step's x tile (plain cached load, independent)
    u64 xq_next = xq;
    if (s < T_SEQ) xq_next = *(const u64*)(xb + (size_t)s * 393216);

    // ---- load h plane words; validate epoch tag; retry stale ----
    const u64* src = hfrag + ((size_t)((s - 1) & 1) * 4 + bg) * 4096;
    const unsigned expt = (((unsigned)(s - 1)) >> 1) & 15u;
    u64 w[22];
    #pragma unroll
    for (int k = 0; k < 22; ++k) {
      int wd = tid + 192 * k;
      w[k] = (wd < 4096) ? cload64(src + wd) : ((u64)expt << 28);
    }
    for (int tries = 0; tries < 20000; ++tries) {
      unsigned bad = 0;
      #pragma unroll
      for (int k = 0; k < 22; ++k)
        bad |= ((((unsigned)(w[k] >> 28)) & 15u) != expt) ? (1u << k) : 0u;
      if (bad == 0) break;
      #pragma unroll
      for (int k = 0; k < 22; ++k) {
        int wd = tid + 192 * k;
        if ((bad & (1u << k)) && wd < 4096) w[k] = cload64(src + wd);
      }
    }
    // ---- unpack q14 -> f16 frag into LDS ----
    #pragma unroll
    for (int k = 0; k < 22; ++k) {
      int wd = tid + 192 * k;
      if (wd < 4096) {
        unsigned lo = (unsigned)w[k], hi = (unsigned)(w[k] >> 32);
        h16x4 o;
        o[0] = (h16)((float)(((int)(lo << 18)) >> 18) * S);
        o[1] = (h16)((float)(((int)(lo << 4)) >> 18) * S);
        o[2] = (h16)((float)(((int)(hi << 18)) >> 18) * S);
        o[3] = (h16)((float)(((int)(hi << 4)) >> 18) * S);
        *(h16x4*)&hstage[wd * 4] = o;
      }
    }
    __syncthreads();   // b1: h staged

    // ---- hid = h_f16 @ U_gate : 32 MFMA, contiguous b128 reads ----
    f32x4 a0 = {}, a1 = {};
    #pragma unroll
    for (int kt = 0; kt < 32; ++kt) {
      h16x8 a = *(const h16x8*)&hstage[(kt * 64 + l) * 8];
      h16x8 b = *(const h16x8*)&Ug[(kt * 64 + l) * 8];
      if (kt & 1) a1 = __builtin_amdgcn_mfma_f32_16x16x32_f16(a, b, a1, 0, 0, 0);
      else        a0 = __builtin_amdgcn_mfma_f32_16x16x32_f16(a, b, a0, 0, 0, 0);
    }
    f32x4 hid;
    #pragma unroll
    for (int i = 0; i < 4; ++i) hid[i] = a0[i] + a1[i];

    H4 xc; xc.q = xq;
    const int p = s & 1;

    if (g == 0) {
      #pragma unroll
      for (int i = 0; i < 4; ++i) {
        float pr = (float)xc.v[i] + hid[i];
        rbuf[p][(rr0 + i) * 17 + cc] = 1.0f / (1.0f + __expf(-pr));
      }
    } else if (g == 1) {
      #pragma unroll
      for (int i = 0; i < 4; ++i) {
        float pu = (float)xc.v[i] + hid[i];
        ubuf[p][(rr0 + i) * 17 + cc] = 1.0f / (1.0f + __expf(-pu));
      }
    }
    __syncthreads();   // b2: r,u visible to wave 2

    if (g == 2) {
      const unsigned tag = (((unsigned)s) >> 1) & 15u;
      #pragma unroll
      for (int i = 0; i < 4; ++i) {
        int rr = rr0 + i;
        float r = rbuf[p][rr * 17 + cc];
        float u = ubuf[p][rr * 17 + cc];
        float z = (float)xc.v[i] + r * hid[i];
        float e = __expf(2.0f * z);
        float c = 1.0f - 2.0f / (e + 1.0f);      // tanh(z)
        float hn = (1.0f - u) * hq[i] + u * c;
        hq[i] = hn;
        int qv = (int)__builtin_rintf(fminf(hn * 8192.0f, 8191.0f));
        tq[rr * 20 + cc] = (unsigned short)(qv & 0x3FFF);
        if (s == T_SEQ) out[(size_t)(bg * 16 + rr) * NH + cg * 16 + cc] = hn;
      }
      // gather 4 cols of row (l>>1)&15 at col base (l>>5)*8+(l&1)*4, pack+tag
      u64 t = *(const u64*)&tq[((l >> 1) & 15) * 20 + (l >> 5) * 8 + (l & 1) * 4];
      unsigned lo = ((unsigned)t & 0x3FFFu)
                  | ((((unsigned)(t >> 16)) & 0x3FFFu) << 14) | (tag << 28);
      unsigned hi = (((unsigned)(t >> 32)) & 0x3FFFu)
                  | ((((unsigned)(t >> 48)) & 0x3FFFu) << 14);
      u64* dst = hfrag + (((size_t)(s & 1) * 4 + bg) * 4096) + cg * 64 + l;
      cstore64(dst, (u64)lo | ((u64)hi << 32));   // self-validating: no drain
    }
    xq = xq_next;
  }
}

// ============================================================
extern "C" void kernel_launch(void* const* d_in, const int* in_sizes, int n_in,
                              void* d_out, int out_size, void* d_ws, size_t ws_size,
                              hipStream_t stream) {
  const float* inp  = (const float*)d_in[0];
  const float* Win  = (const float*)d_in[1];
  const float* Whid = (const float*)d_in[2];
  const float* bstk = (const float*)d_in[3];
  const float* hid0 = (const float*)d_in[4];
  float* out = (float*)d_out;

  char* ws = (char*)d_ws;
  const size_t xBytes = (size_t)T_SEQ * NB * N3H * sizeof(h16);   // 201,326,592
  const size_t hBytes = (size_t)2 * 4 * 4096 * sizeof(u64);       //     262,144
  if (ws_size < xBytes + hBytes) return;

  h16* x = (h16*)ws;
  u64* hfrag = (u64*)(ws + xBytes);

  gru_init_h<<<dim3(16384 / 256), dim3(256), 0, stream>>>(hid0, hfrag);

  dim3 g1(32768 / P1_BM, N3H / 128);
  gru_xgemm<<<g1, dim3(256), 0, stream>>>(inp, Win, bstk, x);

  gru_steps<<<dim3(256), dim3(192), 0, stream>>>(Whid, x, hfrag, hid0, out);
}